// Round 17
// baseline (60.044 us; speedup 1.0000x reference)
//
#include <hip/hip_runtime.h>
#include <hip/hip_fp16.h>

#define D       128
#define NROWS   100000
#define NET     (NROWS / 16)       // 6250 E-tiles (16 rows each), exact
#define NBE     ((NET + 3) / 4)    // 1563 E-blocks (4 tiles each, wave-pairs)
#define NBN     (NROWS / 16)       // 6250 N-blocks

typedef __attribute__((ext_vector_type(8))) _Float16 f16x8;
typedef __attribute__((ext_vector_type(4))) _Float16 f16x4;
typedef __attribute__((ext_vector_type(4))) float    f32x4;

union F16x8U { _Float16 h[8]; f16x8 v; };
union F16x4U { _Float16 h[4]; f16x4 v; };
union F32x4U { float f[4]; f32x4 v; };

typedef __attribute__((address_space(1))) const void gvoid;
typedef __attribute__((address_space(3))) void       lvoid;

// ---------------------------------------------------------------------------
// Kernel 0: metric -> fragment-ordered fp16 B-fragments (single term, 32 KB).
// Slot q = (kk*8+cf)*64+lane holds M[k0+j][col], col = cf*16+(lane&15),
// k0 = kk*32+(lane>>4)*8 — the verified 16x16x32 MFMA B-operand layout.
// ---------------------------------------------------------------------------
__global__ __launch_bounds__(256) void convert_M16(
    const float* __restrict__ M, _Float16* __restrict__ mh)
{
    const int q    = blockIdx.x * 256 + threadIdx.x;  // [0, 2048)
    const int kk   = q >> 9;
    const int cf   = (q >> 6) & 7;
    const int lane = q & 63;
    const int col  = cf * 16 + (lane & 15);
    const int k0   = kk * 32 + (lane >> 4) * 8;

    F16x8U h;
    #pragma unroll
    for (int j = 0; j < 8; ++j) h.h[j] = (_Float16)M[(k0 + j) * D + col];
    *(f16x8*)(mh + q * 8) = h.v;
}

// ---------------------------------------------------------------------------
// Kernel 1: E-GEMM at 32 waves/CU. 512-thr blocks (8 waves) + 32 KB LDS (M)
// -> 4 blocks/CU; __launch_bounds__(512,8) caps VGPR at 64 so all 8 waves/
// SIMD are resident. Each 16-row tile is computed by a WAVE-PAIR: wave
// (t2 = w>>1, h = w&1) covers cols [h*64, h*64+64) -> acc[4] = 16 VGPR.
// Per kk: 2 dwordx4 A-loads (pair-waves read identical lines back-to-back
// -> L2-merged), cvt fp16, 4 conflict-free ds_read_b128 B-frags, 4 MFMAs.
// Epilogue: pi-ordered f16x4 stores. pi(c) = (c&15)*8 + (c>>4).
// ---------------------------------------------------------------------------
__global__ __launch_bounds__(512, 8) void gemm_E_hi(
    const float* __restrict__ E, const _Float16* __restrict__ mh,
    _Float16* __restrict__ Ep)
{
    __shared__ _Float16 smM[2048 * 8];   // 32 KB, B-fragment slots

    const int tid  = threadIdx.x;
    const int lane = tid & 63;
    const int w    = tid >> 6;           // 0..7
    const int lrow = lane & 15;
    const int lk   = lane >> 4;

    // Stage M fragments (2048 slots, 512 lanes -> 4 iters; proven drain).
    #pragma unroll
    for (int it = 0; it < 4; ++it) {
        const int slot = it * 512 + w * 64 + lane;
        __builtin_amdgcn_global_load_lds(
            (gvoid*)(mh + slot * 8), (lvoid*)(smM + (it * 512 + w * 64) * 8),
            16, 0, 0);
    }
    asm volatile("s_waitcnt vmcnt(0)" ::: "memory");
    __syncthreads();

    const f16x8* Bh = (const f16x8*)smM;   // [(kk*8+cf)*64 + lane]

    const int tile = (int)blockIdx.x * 4 + (w >> 1);
    if (tile >= NET) return;
    const int h   = w & 1;                 // column half
    const int row = tile * 16 + lrow;

    f32x4 acc[4];
    #pragma unroll
    for (int c = 0; c < 4; ++c) acc[c] = (f32x4){0.f, 0.f, 0.f, 0.f};

    #pragma unroll
    for (int kk = 0; kk < 4; ++kk) {
        const float* p = E + (size_t)row * D + kk * 32 + lk * 8;
        F32x4U x, y;
        x.v = *(const f32x4*)p;
        y.v = *(const f32x4*)(p + 4);
        F16x8U a16;
        #pragma unroll
        for (int j = 0; j < 4; ++j) {
            a16.h[j]     = (_Float16)x.f[j];
            a16.h[j + 4] = (_Float16)y.f[j];
        }
        #pragma unroll
        for (int c = 0; c < 4; ++c) {
            const int cf = h * 4 + c;
            acc[c] = __builtin_amdgcn_mfma_f32_16x16x32_f16(
                a16.v, Bh[(kk * 8 + cf) * 64 + lane], acc[c], 0, 0, 0);
        }
    }

    // Epilogue: C/D col = lane&15, row = lk*4+i (m89-verified). pi puts this
    // wave's 4 cf-values contiguous at Ep[ro*128 + lrow*8 + h*4].
    #pragma unroll
    for (int i = 0; i < 4; ++i) {
        const int ro = tile * 16 + lk * 4 + i;
        F16x4U o;
        #pragma unroll
        for (int c = 0; c < 4; ++c) o.h[c] = (_Float16)acc[c][i];
        *(f16x4*)(Ep + (size_t)ro * D + lrow * 8 + h * 4) = o.v;
    }
}

// ---------------------------------------------------------------------------
// Kernel 2: N -> fp16 in pi order (proven R6 pattern). LDS-free, tiny VGPR
// -> 32 waves/CU capable. 16 rows/block; thread (row,l16) reads 8 dwords at
// stride 64B (coalesced per 16-lane group) -> one 16B store.
// ---------------------------------------------------------------------------
__global__ __launch_bounds__(256, 8) void conv_N(
    const float* __restrict__ N, _Float16* __restrict__ Np)
{
    const int l16 = threadIdx.x & 15;
    const int row = blockIdx.x * 16 + (threadIdx.x >> 4);   // exact
    const float* src = N + (size_t)row * D + l16;
    F16x8U o;
    #pragma unroll
    for (int k = 0; k < 8; ++k) o.h[k] = (_Float16)src[16 * k];
    *(f16x8*)(Np + (size_t)row * D + l16 * 8) = o.v;
}

// ---------------------------------------------------------------------------
// Kernel 3: out[b] = sigmoid(2 * dot(Ep[xs[b]], Np[ys[b]]) - 1).
// Both tables fp16 in pi order (dot order-invariant). 16 lanes/output,
// 2 outputs per lane-group, one dwordx4 per table per output, fp32 accum.
// ---------------------------------------------------------------------------
__global__ __launch_bounds__(256) void gather_dot16(
    const int* __restrict__ xs, const int* __restrict__ ys,
    const _Float16* __restrict__ Ep, const _Float16* __restrict__ Np,
    float* __restrict__ out)
{
    const int tid = threadIdx.x;
    const int o0  = blockIdx.x * 32 + (tid >> 4) * 2;
    const int l   = tid & 15;

    const int x0 = xs[o0], x1 = xs[o0 + 1];
    const int y0 = ys[o0], y1 = ys[o0 + 1];

    const f16x8 a0 = *(const f16x8*)(Ep + (size_t)x0 * D + l * 8);
    const f16x8 b0 = *(const f16x8*)(Np + (size_t)y0 * D + l * 8);
    const f16x8 a1 = *(const f16x8*)(Ep + (size_t)x1 * D + l * 8);
    const f16x8 b1 = *(const f16x8*)(Np + (size_t)y1 * D + l * 8);

    float r0 = 0.f, r1 = 0.f;
    #pragma unroll
    for (int j = 0; j < 8; ++j) {
        r0 += (float)a0[j] * (float)b0[j];
        r1 += (float)a1[j] * (float)b1[j];
    }

    r0 += __shfl_xor(r0, 1); r1 += __shfl_xor(r1, 1);
    r0 += __shfl_xor(r0, 2); r1 += __shfl_xor(r1, 2);
    r0 += __shfl_xor(r0, 4); r1 += __shfl_xor(r1, 4);
    r0 += __shfl_xor(r0, 8); r1 += __shfl_xor(r1, 8);

    if (l == 0) {
        float2 v;
        v.x = 1.0f / (1.0f + __expf(1.0f - 2.0f * r0));
        v.y = 1.0f / (1.0f + __expf(1.0f - 2.0f * r1));
        *(float2*)(out + o0) = v;
    }
}

extern "C" void kernel_launch(void* const* d_in, const int* in_sizes, int n_in,
                              void* d_out, int out_size, void* d_ws, size_t ws_size,
                              hipStream_t stream) {
    const int*   xs     = (const int*)d_in[0];
    const int*   ys     = (const int*)d_in[1];
    const float* metric = (const float*)d_in[2];
    const float* EMBEDM = (const float*)d_in[3];
    const float* NEGEM  = (const float*)d_in[4];
    float*       out    = (float*)d_out;

    const int B = in_sizes[0];  // 262144

    // d_ws layout: Np16 25.6MB @0, Ep16 25.6MB @32MB, M-fragments 32KB @64MB.
    char* ws = (char*)d_ws;
    _Float16* Np = (_Float16*)ws;
    _Float16* Ep = (_Float16*)(ws + (32u << 20));
    _Float16* mh = (_Float16*)(ws + (64u << 20));

    convert_M16<<<8, 256, 0, stream>>>(metric, mh);

    gemm_E_hi<<<NBE, 512, 0, stream>>>(EMBEDM, mh, Ep);

    conv_N<<<NBN, 256, 0, stream>>>(NEGEM, Np);

    gather_dot16<<<B / 32, 256, 0, stream>>>(xs, ys, Ep, Np, out);
}

// Round 18
// 53.058 us; speedup vs baseline: 1.1317x; 1.1317x over previous
//
#include <hip/hip_runtime.h>
#include <hip/hip_fp16.h>

#define D        128
#define NROWS    100000
#define NET      (NROWS / 16)      // 6250 16-row tiles per table
#define NUNITS   (2 * NET)         // 12500 units: even -> E-tile u>>1, odd -> N-tile u>>1
#define GRID_P   768               // 3 blocks/CU (48 KB LDS each)
#define NWAVES   (GRID_P * 4)      // 3072 waves; stride keeps unit parity per wave

typedef __attribute__((ext_vector_type(8))) _Float16 f16x8;
typedef __attribute__((ext_vector_type(4))) _Float16 f16x4;
typedef __attribute__((ext_vector_type(4))) float    f32x4;

union F16x8U { _Float16 h[8]; f16x8 v; };
union F16x4U { _Float16 h[4]; f16x4 v; };
union F32x4U { float f[4]; f32x4 v; };

typedef __attribute__((address_space(1))) const void gvoid;
typedef __attribute__((address_space(3))) void       lvoid;

// ---------------------------------------------------------------------------
// Kernel 0: metric -> fragment-ordered fp16 B-fragments (single term, 32 KB).
// Slot q = (kk*8+cf)*64+lane holds M[k0+j][col], col = cf*16+(lane&15),
// k0 = kk*32+(lane>>4)*8 — the verified 16x16x32 MFMA B-operand layout.
// ---------------------------------------------------------------------------
__global__ __launch_bounds__(256) void convert_M16(
    const float* __restrict__ M, _Float16* __restrict__ mh)
{
    const int q    = blockIdx.x * 256 + threadIdx.x;  // [0, 2048)
    const int kk   = q >> 9;
    const int cf   = (q >> 6) & 7;
    const int lane = q & 63;
    const int col  = cf * 16 + (lane & 15);
    const int k0   = kk * 32 + (lane >> 4) * 8;

    F16x8U h;
    #pragma unroll
    for (int j = 0; j < 8; ++j) h.h[j] = (_Float16)M[(k0 + j) * D + col];
    *(f16x8*)(mh + q * 8) = h.v;
}

// ---------------------------------------------------------------------------
// Kernel 1: persistent prep with 2-deep per-wave pipeline.
// Wave parity (gw&1) is invariant under the grid stride (NWAVES even):
//   even gw -> E-waves, odd gw -> N-waves. Each iteration processes TWO
//   units: ALL 16 load instructions issue first (sched_barrier(0) pins them
//   against re-sinking — the R11 failure mode), doubling in-flight bytes.
//
// E-tile (R16-proven math): contiguous f32x4 loads -> cvt fp16 -> XOR-
//   swizzled ds_write_b64 into 4KB wave-private scratch -> conflict-free
//   ds_read_b128 A-frags -> 32 MFMAs (M fragments in block-shared 32KB LDS)
//   -> pi-ordered f16x8 epilogue. pi(c) = (c&15)*8 + (c>>4).
//
// N-tile (R6-proven, direct — no LDS bounce, no bank conflicts): per group
//   g=0..3, lane (row = g*4 + lane>>4, l16 = lane&15) reads 8 dwords at
//   stride 64B -> one pi-ordered f16x8 store.
// ---------------------------------------------------------------------------
__global__ __launch_bounds__(256, 3) void prep_pipe(
    const float* __restrict__ E, const float* __restrict__ N,
    const _Float16* __restrict__ mh,
    _Float16* __restrict__ Ep, _Float16* __restrict__ Np)
{
    __shared__ _Float16 smM[2048 * 8];   // 32 KB M B-fragment slots
    __shared__ _Float16 scr[4][2048];    // 4 KB per wave (E-waves only)

    const int tid  = threadIdx.x;
    const int lane = tid & 63;
    const int w    = tid >> 6;
    const int lrow = lane & 15;
    const int lk   = lane >> 4;

    // Stage M fragments once per block (proven drain).
    #pragma unroll
    for (int it = 0; it < 8; ++it) {
        const int slot = it * 256 + w * 64 + lane;
        __builtin_amdgcn_global_load_lds(
            (gvoid*)(mh + slot * 8), (lvoid*)(smM + (it * 256 + w * 64) * 8),
            16, 0, 0);
    }
    asm volatile("s_waitcnt vmcnt(0)" ::: "memory");
    __syncthreads();

    const f16x8* Bh = (const f16x8*)smM;   // [(kk*8+cf)*64 + lane]
    _Float16*    S  = scr[w];

    const int gw = (int)blockIdx.x * 4 + w;   // 0..3071

    if ((gw & 1) == 0) {
        // ================= E-waves =================
        #pragma unroll 1
        for (int u = gw; u < NUNITS; u += 2 * NWAVES) {
            const int  tA   = u >> 1;
            const int  uB   = u + NWAVES;
            const bool hasB = uB < NUNITS;
            const int  tB   = hasB ? (uB >> 1) : tA;

            // ---- issue ALL loads (A then B), then pin ----
            f32x4 va[8], vb[8];
            #pragma unroll
            for (int i = 0; i < 8; ++i)
                va[i] = *(const f32x4*)(E + (size_t)tA * 2048 + i * 256 + lane * 4);
            if (hasB) {
                #pragma unroll
                for (int i = 0; i < 8; ++i)
                    vb[i] = *(const f32x4*)(E + (size_t)tB * 2048 + i * 256 + lane * 4);
            }
            __builtin_amdgcn_sched_barrier(0);

            // ---- process A, then B (scratch reuse safe: per-wave DS ops
            //      are in-order; A's reads precede B's writes) ----
            #pragma unroll
            for (int half = 0; half < 2; ++half) {
                if (half == 1 && !hasB) break;
                const int t = (half == 0) ? tA : tB;

                #pragma unroll
                for (int i = 0; i < 8; ++i) {
                    const int f   = i * 256 + lane * 4;
                    const int row = f >> 7;
                    const int col = f & 127;
                    F32x4U v; v.v = (half == 0) ? va[i] : vb[i];
                    F16x4U h4;
                    h4.h[0] = (_Float16)v.f[0]; h4.h[1] = (_Float16)v.f[1];
                    h4.h[2] = (_Float16)v.f[2]; h4.h[3] = (_Float16)v.f[3];
                    const int tsl = (col >> 3) ^ row;
                    *(f16x4*)(S + row * 128 + tsl * 8 + (col & 7)) = h4.v;
                }
                asm volatile("s_waitcnt lgkmcnt(0)" ::: "memory");
                __builtin_amdgcn_sched_barrier(0);

                f32x4 acc[8];
                #pragma unroll
                for (int cf = 0; cf < 8; ++cf) acc[cf] = (f32x4){0.f, 0.f, 0.f, 0.f};

                #pragma unroll
                for (int kk = 0; kk < 4; ++kk) {
                    const f16x8 a16 =
                        *(const f16x8*)(S + lrow * 128 + ((kk * 4 + lk) ^ lrow) * 8);
                    #pragma unroll
                    for (int cf = 0; cf < 8; ++cf)
                        acc[cf] = __builtin_amdgcn_mfma_f32_16x16x32_f16(
                            a16, Bh[(kk * 8 + cf) * 64 + lane], acc[cf], 0, 0, 0);
                }

                #pragma unroll
                for (int i = 0; i < 4; ++i) {
                    const int ro = t * 16 + lk * 4 + i;
                    F16x8U o;
                    #pragma unroll
                    for (int cf = 0; cf < 8; ++cf) o.h[cf] = (_Float16)acc[cf][i];
                    *(f16x8*)(Ep + (size_t)ro * D + lrow * 8) = o.v;
                }
            }
        }
    } else {
        // ================= N-waves =================
        #pragma unroll 1
        for (int u = gw; u < NUNITS; u += 2 * NWAVES) {
            const int  tA   = u >> 1;
            const int  uB   = u + NWAVES;
            const bool hasB = uB < NUNITS;
            const int  tB   = hasB ? (uB >> 1) : tA;

            // ---- issue ALL 64 dword loads (A then B), then pin ----
            float da[32], db[32];
            #pragma unroll
            for (int g = 0; g < 4; ++g) {
                const float* src = N + ((size_t)tA * 16 + g * 4 + lk) * D + lrow;
                #pragma unroll
                for (int k = 0; k < 8; ++k) da[g * 8 + k] = src[16 * k];
            }
            if (hasB) {
                #pragma unroll
                for (int g = 0; g < 4; ++g) {
                    const float* src = N + ((size_t)tB * 16 + g * 4 + lk) * D + lrow;
                    #pragma unroll
                    for (int k = 0; k < 8; ++k) db[g * 8 + k] = src[16 * k];
                }
            }
            __builtin_amdgcn_sched_barrier(0);

            // ---- cvt + pi-ordered stores ----
            #pragma unroll
            for (int g = 0; g < 4; ++g) {
                F16x8U o;
                #pragma unroll
                for (int k = 0; k < 8; ++k) o.h[k] = (_Float16)da[g * 8 + k];
                *(f16x8*)(Np + ((size_t)tA * 16 + g * 4 + lk) * D + lrow * 8) = o.v;
            }
            if (hasB) {
                #pragma unroll
                for (int g = 0; g < 4; ++g) {
                    F16x8U o;
                    #pragma unroll
                    for (int k = 0; k < 8; ++k) o.h[k] = (_Float16)db[g * 8 + k];
                    *(f16x8*)(Np + ((size_t)tB * 16 + g * 4 + lk) * D + lrow * 8) = o.v;
                }
            }
        }
    }
}

// ---------------------------------------------------------------------------
// Kernel 2: out[b] = sigmoid(2 * dot(Ep[xs[b]], Np[ys[b]]) - 1).
// Both tables fp16 in pi order (dot order-invariant). 16 lanes/output,
// 2 outputs per lane-group, one dwordx4 per table per output, fp32 accum.
// ---------------------------------------------------------------------------
__global__ __launch_bounds__(256) void gather_dot16(
    const int* __restrict__ xs, const int* __restrict__ ys,
    const _Float16* __restrict__ Ep, const _Float16* __restrict__ Np,
    float* __restrict__ out)
{
    const int tid = threadIdx.x;
    const int o0  = blockIdx.x * 32 + (tid >> 4) * 2;
    const int l   = tid & 15;

    const int x0 = xs[o0], x1 = xs[o0 + 1];
    const int y0 = ys[o0], y1 = ys[o0 + 1];

    const f16x8 a0 = *(const f16x8*)(Ep + (size_t)x0 * D + l * 8);
    const f16x8 b0 = *(const f16x8*)(Np + (size_t)y0 * D + l * 8);
    const f16x8 a1 = *(const f16x8*)(Ep + (size_t)x1 * D + l * 8);
    const f16x8 b1 = *(const f16x8*)(Np + (size_t)y1 * D + l * 8);

    float r0 = 0.f, r1 = 0.f;
    #pragma unroll
    for (int j = 0; j < 8; ++j) {
        r0 += (float)a0[j] * (float)b0[j];
        r1 += (float)a1[j] * (float)b1[j];
    }

    r0 += __shfl_xor(r0, 1); r1 += __shfl_xor(r1, 1);
    r0 += __shfl_xor(r0, 2); r1 += __shfl_xor(r1, 2);
    r0 += __shfl_xor(r0, 4); r1 += __shfl_xor(r1, 4);
    r0 += __shfl_xor(r0, 8); r1 += __shfl_xor(r1, 8);

    if (l == 0) {
        float2 v;
        v.x = 1.0f / (1.0f + __expf(1.0f - 2.0f * r0));
        v.y = 1.0f / (1.0f + __expf(1.0f - 2.0f * r1));
        *(float2*)(out + o0) = v;
    }
}

extern "C" void kernel_launch(void* const* d_in, const int* in_sizes, int n_in,
                              void* d_out, int out_size, void* d_ws, size_t ws_size,
                              hipStream_t stream) {
    const int*   xs     = (const int*)d_in[0];
    const int*   ys     = (const int*)d_in[1];
    const float* metric = (const float*)d_in[2];
    const float* EMBEDM = (const float*)d_in[3];
    const float* NEGEM  = (const float*)d_in[4];
    float*       out    = (float*)d_out;

    const int B = in_sizes[0];  // 262144

    // d_ws layout: Np16 25.6MB @0, Ep16 25.6MB @32MB, M-fragments 32KB @64MB.
    char* ws = (char*)d_ws;
    _Float16* Np = (_Float16*)ws;
    _Float16* Ep = (_Float16*)(ws + (32u << 20));
    _Float16* mh = (_Float16*)(ws + (64u << 20));

    convert_M16<<<8, 256, 0, stream>>>(metric, mh);

    prep_pipe<<<GRID_P, 256, 0, stream>>>(EMBEDM, NEGEM, mh, Ep, Np);

    gather_dot16<<<B / 32, 256, 0, stream>>>(xs, ys, Ep, Np, out);
}

// Round 19
// 51.279 us; speedup vs baseline: 1.1709x; 1.0347x over previous
//
#include <hip/hip_runtime.h>
#include <hip/hip_fp16.h>

#define D        128
#define NROWS    100000
#define NET      (NROWS / 16)      // 6250 E-tiles (16 rows each), exact
#define GRID_P   768               // 3 blocks/CU (48 KB LDS each)
#define NWAVES   (GRID_P * 4)      // 3072 grid-striding waves

typedef __attribute__((ext_vector_type(8))) _Float16 f16x8;
typedef __attribute__((ext_vector_type(4))) _Float16 f16x4;
typedef __attribute__((ext_vector_type(4))) float    f32x4;

union F16x8U { _Float16 h[8]; f16x8 v; };
union F16x4U { _Float16 h[4]; f16x4 v; };
union F32x4U { float f[4]; f32x4 v; };

typedef __attribute__((address_space(1))) const void gvoid;
typedef __attribute__((address_space(3))) void       lvoid;

// ---------------------------------------------------------------------------
// Kernel 0: metric -> fragment-ordered fp16 B-fragments (single term, 32 KB).
// Slot q = (kk*8+cf)*64+lane holds M[k0+j][col], col = cf*16+(lane&15),
// k0 = kk*32+(lane>>4)*8 — the verified 16x16x32 MFMA B-operand layout.
// ---------------------------------------------------------------------------
__global__ __launch_bounds__(256) void convert_M16(
    const float* __restrict__ M, _Float16* __restrict__ mh)
{
    const int q    = blockIdx.x * 256 + threadIdx.x;  // [0, 2048)
    const int kk   = q >> 9;
    const int cf   = (q >> 6) & 7;
    const int lane = q & 63;
    const int col  = cf * 16 + (lane & 15);
    const int k0   = kk * 32 + (lane >> 4) * 8;

    F16x8U h;
    #pragma unroll
    for (int j = 0; j < 8; ++j) h.h[j] = (_Float16)M[(k0 + j) * D + col];
    *(f16x8*)(mh + q * 8) = h.v;
}

// ---------------------------------------------------------------------------
// Kernel 1: E' = E @ M only (N stays fp32; its convert traffic is deleted —
// the gather reads N directly from the L3-served fast path).
// R16-proven E-path, persistent waves, no hot-loop barriers:
//   contiguous f32x4 loads -> cvt fp16 -> XOR-swizzled ds_write_b64 into a
//   4KB wave-private scratch -> conflict-free ds_read_b128 A-frags ->
//   32 MFMAs (M fragments in block-shared 32KB LDS) -> pi-ordered f16x8
//   epilogue stores. pi(c) = (c&15)*8 + (c>>4).
// LDS: 32KB (M) + 4 x 4KB (scratch) = 48KB -> 3 blocks/CU, 12 waves/CU.
// ---------------------------------------------------------------------------
__global__ __launch_bounds__(256, 3) void gemm_E_pers(
    const float* __restrict__ E, const _Float16* __restrict__ mh,
    _Float16* __restrict__ Ep)
{
    __shared__ _Float16 smM[2048 * 8];   // 32 KB M B-fragment slots
    __shared__ _Float16 scr[4][2048];    // 4 KB per wave

    const int tid  = threadIdx.x;
    const int lane = tid & 63;
    const int w    = tid >> 6;
    const int lrow = lane & 15;
    const int lk   = lane >> 4;

    // Stage M fragments once per block (proven drain).
    #pragma unroll
    for (int it = 0; it < 8; ++it) {
        const int slot = it * 256 + w * 64 + lane;
        __builtin_amdgcn_global_load_lds(
            (gvoid*)(mh + slot * 8), (lvoid*)(smM + (it * 256 + w * 64) * 8),
            16, 0, 0);
    }
    asm volatile("s_waitcnt vmcnt(0)" ::: "memory");
    __syncthreads();

    const f16x8* Bh = (const f16x8*)smM;   // [(kk*8+cf)*64 + lane]
    _Float16*    S  = scr[w];

    const int gw = (int)blockIdx.x * 4 + w;   // 0..3071

    #pragma unroll 1
    for (int t = gw; t < NET; t += NWAVES) {
        // Contiguous loads + cvt + swizzled scratch writes.
        #pragma unroll
        for (int i = 0; i < 8; ++i) {
            const int f   = i * 256 + lane * 4;   // flat float idx in tile
            const int row = f >> 7;
            const int col = f & 127;
            F32x4U v; v.v = *(const f32x4*)(E + (size_t)t * 2048 + f);
            F16x4U h4;
            h4.h[0] = (_Float16)v.f[0]; h4.h[1] = (_Float16)v.f[1];
            h4.h[2] = (_Float16)v.f[2]; h4.h[3] = (_Float16)v.f[3];
            const int tsl = (col >> 3) ^ row;     // XOR swizzle, bijective
            *(f16x4*)(S + row * 128 + tsl * 8 + (col & 7)) = h4.v;
        }
        asm volatile("s_waitcnt lgkmcnt(0)" ::: "memory");
        __builtin_amdgcn_sched_barrier(0);

        f32x4 acc[8];
        #pragma unroll
        for (int cf = 0; cf < 8; ++cf) acc[cf] = (f32x4){0.f, 0.f, 0.f, 0.f};

        #pragma unroll
        for (int kk = 0; kk < 4; ++kk) {
            // A-frag: row lrow, slot (kk*4+lk)^lrow -> cols kk*32+lk*8..+7
            const f16x8 a16 =
                *(const f16x8*)(S + lrow * 128 + ((kk * 4 + lk) ^ lrow) * 8);
            #pragma unroll
            for (int cf = 0; cf < 8; ++cf)
                acc[cf] = __builtin_amdgcn_mfma_f32_16x16x32_f16(
                    a16, Bh[(kk * 8 + cf) * 64 + lane], acc[cf], 0, 0, 0);
        }

        // Epilogue: C/D col = lrow, row = lk*4+i (m89-verified); pi makes the
        // 8 cf-values contiguous -> one f16x8 store per i.
        #pragma unroll
        for (int i = 0; i < 4; ++i) {
            const int ro = t * 16 + lk * 4 + i;
            F16x8U o;
            #pragma unroll
            for (int cf = 0; cf < 8; ++cf) o.h[cf] = (_Float16)acc[cf][i];
            *(f16x8*)(Ep + (size_t)ro * D + lrow * 8) = o.v;
        }
        // Scratch reuse across iterations is safe: per-wave DS ops are
        // in-order and reads above are lgkm-drained before next writes.
    }
}

// ---------------------------------------------------------------------------
// Kernel 2 (R8-proven): out[b] = sigmoid(2 * dot(Ep16[xs[b]], N[ys[b]]) - 1).
// Ep fp16 in pi order: lane l's f16x8 slot j holds col c = l + 16j, pairing
// with N[y][l + 16j] (fp32, exact; coalescing to 64B segments per 16-lane
// group). 2 outputs per lane-group, fp32 accumulate.
// ---------------------------------------------------------------------------
__global__ __launch_bounds__(256) void gather_dotN(
    const int* __restrict__ xs, const int* __restrict__ ys,
    const _Float16* __restrict__ Ep, const float* __restrict__ N,
    float* __restrict__ out)
{
    const int tid = threadIdx.x;
    const int o0  = blockIdx.x * 32 + (tid >> 4) * 2;
    const int l   = tid & 15;

    const int x0 = xs[o0], x1 = xs[o0 + 1];
    const int y0 = ys[o0], y1 = ys[o0 + 1];

    const f16x8 a0 = *(const f16x8*)(Ep + (size_t)x0 * D + l * 8);
    const f16x8 a1 = *(const f16x8*)(Ep + (size_t)x1 * D + l * 8);
    const float* n0 = N + (size_t)y0 * D + l;
    const float* n1 = N + (size_t)y1 * D + l;

    float r0 = 0.f, r1 = 0.f;
    #pragma unroll
    for (int j = 0; j < 8; ++j) {
        r0 += (float)a0[j] * n0[16 * j];
        r1 += (float)a1[j] * n1[16 * j];
    }

    r0 += __shfl_xor(r0, 1); r1 += __shfl_xor(r1, 1);
    r0 += __shfl_xor(r0, 2); r1 += __shfl_xor(r1, 2);
    r0 += __shfl_xor(r0, 4); r1 += __shfl_xor(r1, 4);
    r0 += __shfl_xor(r0, 8); r1 += __shfl_xor(r1, 8);

    if (l == 0) {
        float2 v;
        v.x = 1.0f / (1.0f + __expf(1.0f - 2.0f * r0));
        v.y = 1.0f / (1.0f + __expf(1.0f - 2.0f * r1));
        *(float2*)(out + o0) = v;
    }
}

extern "C" void kernel_launch(void* const* d_in, const int* in_sizes, int n_in,
                              void* d_out, int out_size, void* d_ws, size_t ws_size,
                              hipStream_t stream) {
    const int*   xs     = (const int*)d_in[0];
    const int*   ys     = (const int*)d_in[1];
    const float* metric = (const float*)d_in[2];
    const float* EMBEDM = (const float*)d_in[3];
    const float* NEGEM  = (const float*)d_in[4];
    float*       out    = (float*)d_out;

    const int B = in_sizes[0];  // 262144

    // d_ws layout: Ep16 25.6MB @0, M-fragments 32KB @64MB.
    char* ws = (char*)d_ws;
    _Float16* Ep = (_Float16*)ws;
    _Float16* mh = (_Float16*)(ws + (64u << 20));

    convert_M16<<<8, 256, 0, stream>>>(metric, mh);

    gemm_E_pers<<<GRID_P, 256, 0, stream>>>(EMBEDM, mh, Ep);

    gather_dotN<<<B / 32, 256, 0, stream>>>(xs, ys, Ep, NEGEM, out);
}